// Round 18
// baseline (100.934 us; speedup 1.0000x reference)
//
#include <hip/hip_runtime.h>

#define BB 2
#define NN 1024
#define FF 128
#define H1 64
#define H2 32
#define XPAD 136  // x-row stride in f16 (128+8)
#define PAD 72    // p-row stride in f16 (64+8)
#define REPS 16   // INSTRUMENTATION: stage+phaseA repeat (idempotent writes)

typedef __attribute__((ext_vector_type(4))) _Float16 half4;   // 4 f16 (8B)
typedef __attribute__((ext_vector_type(8))) _Float16 half8;   // 8 f16 (4 VGPR)
typedef __attribute__((ext_vector_type(16))) float f32x16;    // 32x32 MFMA acc
typedef __attribute__((ext_vector_type(2))) float f32x2;      // v_pk_*_f32

// e = relu(a + b) in packed f16: 4x v_pk_add_f16 + 4x v_pk_max_f16
__device__ inline half8 addrelu8(half8 a, half8 b) {
    half8 s = a + b;
    const half8 z = {};
    return __builtin_elementwise_max(s, z);
}

// ---------------------------------------------------------------------------
// INSTRUMENTATION ROUND (R18) on the R13 kernel (22.8us best; R17's
// j-consolidation regressed +2.0 -> LDS-broadcast-BW theory dead, reverted).
// Goal: split A+stage = 11.1us into cold-latency vs issue components.
// {stage + phase A} repeated REPS=16x: rep 1 cold, reps 2-16 L2/L3-warm.
//   slope = (dur16 - 22.8)/15 = WARM stage+A cost.
// Branches: slope>=8 -> A issue-bound even warm -> R19 cuts A's inst count
//           (64 scalar loads + 64 cvt per wave is the target);
//           slope<=4 -> 11.1 is mostly unavoidable cold first-touch ->
//           near practical ceiling.
// All rep writes idempotent (same values); per-rep asm memory clobber stops
// cross-rep CSE (rule #17); extra barrier per rep prevents stage(n+1)
// racing phaseA(n) reads. Phase B + output identical to R13 -> test passes.
// ---------------------------------------------------------------------------
__global__ __launch_bounds__(512, 2) void fused_kernel(
    const float* __restrict__ x, const float* __restrict__ W1,
    const float* __restrict__ b1, const float* __restrict__ W2,
    const float* __restrict__ b2, const float* __restrict__ W3,
    const float* __restrict__ b3, float* __restrict__ out)
{
    __shared__ __align__(16) _Float16 xlds[128][XPAD];  // 34.8 KB staged x
    __shared__ __align__(16) _Float16 plds[64][PAD];    // 9.2 KB pib rows
    __shared__ __align__(16) _Float16 pjlds[64][PAD];   // 9.2 KB pj rows

    const int tid  = threadIdx.x;
    const int lane = tid & 63;
    const int wv   = tid >> 6;                // 0..7
    const int bid  = blockIdx.x;

    const int b   = bid >> 8;                 // 256 blocks per batch
    const int rem = bid & 255;
    const int i0  = (rem >> 4) * 64;          // 16 i-tiles (64 rows each)
    const int j0  = (rem & 15) * 64;          // 16 j-tiles (64 cols each)
    const int jn  = lane & 31;                // m/n lane index
    const int hi  = lane >> 5;                // k-group half
    const int m   = jn;

    // ============ {stage + phase A} x REPS (instrumented) =================
    #pragma unroll 1
    for (int rep = 0; rep < REPS; ++rep) {
        asm volatile("" ::: "memory");        // no cross-rep CSE (rule #17)

        // ---- stage: 128 x-rows -> xlds (coalesced, f16) ----
        {
            const int xb_i = b * NN + i0, xb_j = b * NN + j0 - 64;
            #pragma unroll
            for (int it = 0; it < 8; ++it) {
                const int idx = tid + it * 512;
                const int row = idx >> 5, c4 = (idx & 31) * 4;
                const int gr  = (row < 64 ? xb_i : xb_j) + row;
                const float4 v = *(const float4*)(x + (size_t)gr * FF + c4);
                half4 hv = {(_Float16)v.x, (_Float16)v.y,
                            (_Float16)v.z, (_Float16)v.w};
                *(half4*)&xlds[row][c4] = hv;
            }
        }
        __syncthreads();

        // ---- phase A: 8 gemm units, ONE per wave (balanced) ----
        {
            const int xrow0 = ((wv & 2) ? 32 : 0) + ((wv & 4) ? 64 : 0);
            const int htile = wv & 1;
            const int koff  = (wv & 4) ? 0 : FF;
            _Float16* dstbase = (wv & 4) ? &pjlds[xrow0 - 64][0]
                                         : &plds[xrow0][0];
            const float* bias = (wv & 4) ? nullptr : b1;

            f32x16 acc = {};
            #pragma unroll
            for (int ks = 0; ks < 8; ++ks) {
                const int k0 = ks * 16 + hi * 8;
                half8 af;
                const float* wb = W1 + (size_t)(koff + k0) * H1 + htile * 32 + m;
                #pragma unroll
                for (int e = 0; e < 8; ++e)
                    af[e] = (_Float16)wb[(size_t)e * H1];   // coalesced per e
                const half8 bf = *(const half8*)&xlds[xrow0 + m][k0];
                acc = __builtin_amdgcn_mfma_f32_32x32x16_f16(af, bf, acc,
                                                             0, 0, 0);
            }
            _Float16* drow = dstbase + (size_t)m * PAD;     // D col -> LDS row
            #pragma unroll
            for (int q = 0; q < 4; ++q) {                   // packed b64 stores
                half4 hv;
                #pragma unroll
                for (int jj = 0; jj < 4; ++jj) {
                    const int r  = q * 4 + jj;              // hl map [m74/m101]
                    const int hg = htile * 32 + 8 * q + 4 * hi + jj;
                    float v = acc[r];
                    if (bias) v += bias[hg];
                    hv[jj] = (_Float16)v;
                }
                *(half4*)(drow + htile * 32 + 8 * q + 4 * hi) = hv;
            }
        }
        __syncthreads();   // phaseA(n) reads done before stage(n+1) rewrites
    }

    // ============ per-wave edge init (weights straight from global) =======
    half8 wa[4];
    #pragma unroll
    for (int c4 = 0; c4 < 4; ++c4)
        #pragma unroll
        for (int e = 0; e < 8; ++e)
            wa[c4][e] = (_Float16)W2[(16 * c4 + hi * 8 + e) * H2 + jn];

    f32x16 ci;
    #pragma unroll
    for (int r = 0; r < 16; ++r) {           // D row mapping [m74/m101]
        const int row = (r & 3) + 8 * (r >> 2) + 4 * hi;
        ci[r] = b2[row];
    }
    f32x2 w32[8];
    #pragma unroll
    for (int q = 0; q < 8; ++q) {
        const int row = ((2 * q) & 3) + 8 * (q >> 1) + 4 * hi;
        w32[q] = (f32x2){W3[row], W3[row + 1]};
    }
    const float b3v = b3[0];

    const int rowgrp = wv >> 1;
    const int jhalf  = wv & 1;

    const _Float16* pr = &pjlds[jhalf * 32 + jn][hi * 8];
    const half8 qj0 = *(const half8*)(pr);
    const half8 qj1 = *(const half8*)(pr + 16);
    const half8 qj2 = *(const half8*)(pr + 32);
    const half8 qj3 = *(const half8*)(pr + 48);

    auto epi = [&](const f32x16& dd) -> float {
        const f32x2 z2 = {0.f, 0.f};
        f32x2 s[4] = {z2, z2, z2, z2};
        #pragma unroll
        for (int q = 0; q < 8; ++q) {
            f32x2 dp = {dd[2 * q], dd[2 * q + 1]};
            dp = __builtin_elementwise_max(dp, z2);
            s[q & 3] = __builtin_elementwise_fma(dp, w32[q], s[q & 3]);
        }
        const f32x2 t01 = s[0] + s[1];
        const f32x2 t23 = s[2] + s[3];
        const f32x2 tt  = t01 + t23;
        float p = tt[0] + tt[1];
        p += __shfl_xor(p, 32);   // lane-halves hold complementary rows
        return p;
    };

    // ============ phase B: software-pipelined 16 row-steps (R13) ==========
    const _Float16* irbase = &plds[rowgrp * 16][hi * 8];
    float* obase = out + (size_t)(b * NN + i0 + rowgrp * 16) * NN
                       + j0 + jhalf * 32 + jn;

    half8 e0 = addrelu8(qj0, *(const half8*)(irbase));
    half8 e1 = addrelu8(qj1, *(const half8*)(irbase + 16));
    half8 e2 = addrelu8(qj2, *(const half8*)(irbase + 32));
    half8 e3 = addrelu8(qj3, *(const half8*)(irbase + 48));
    f32x16 dP;
    dP = __builtin_amdgcn_mfma_f32_32x32x16_f16(wa[0], e0, ci, 0, 0, 0);
    dP = __builtin_amdgcn_mfma_f32_32x32x16_f16(wa[1], e1, dP, 0, 0, 0);
    dP = __builtin_amdgcn_mfma_f32_32x32x16_f16(wa[2], e2, dP, 0, 0, 0);
    dP = __builtin_amdgcn_mfma_f32_32x32x16_f16(wa[3], e3, dP, 0, 0, 0);
    {
        const _Float16* ir = irbase + PAD;
        e0 = addrelu8(qj0, *(const half8*)(ir));
        e1 = addrelu8(qj1, *(const half8*)(ir + 16));
        e2 = addrelu8(qj2, *(const half8*)(ir + 32));
        e3 = addrelu8(qj3, *(const half8*)(ir + 48));
    }
    float pe = 0.f;

    #pragma unroll 2
    for (int t = 1; t < 16; ++t) {
        const int tn = (t < 15) ? t + 1 : 15;
        const _Float16* ir = irbase + tn * PAD;
        const half8 m0 = *(const half8*)(ir);
        const half8 m1 = *(const half8*)(ir + 16);
        const half8 m2 = *(const half8*)(ir + 32);
        const half8 m3 = *(const half8*)(ir + 48);
        f32x16 d;
        d = __builtin_amdgcn_mfma_f32_32x32x16_f16(wa[0], e0, ci, 0, 0, 0);
        d = __builtin_amdgcn_mfma_f32_32x32x16_f16(wa[1], e1, d,  0, 0, 0);
        d = __builtin_amdgcn_mfma_f32_32x32x16_f16(wa[2], e2, d,  0, 0, 0);
        d = __builtin_amdgcn_mfma_f32_32x32x16_f16(wa[3], e3, d,  0, 0, 0);
        const float p = epi(dP);
        if ((t - 1) & 1) {                   // t even: store pair (t-2, t-1)
            const float v = hi ? p : pe;     // hi half stores the odd row
            obase[(size_t)(t - 2 + hi) * NN] = v + b3v;
        } else {
            pe = p;
        }
        e0 = addrelu8(qj0, m0);
        e1 = addrelu8(qj1, m1);
        e2 = addrelu8(qj2, m2);
        e3 = addrelu8(qj3, m3);
        dP = d;
    }
    {
        const float p = epi(dP);
        const float v = hi ? p : pe;
        obase[(size_t)(14 + hi) * NN] = v + b3v;
    }
}

extern "C" void kernel_launch(void* const* d_in, const int* in_sizes, int n_in,
                              void* d_out, int out_size, void* d_ws, size_t ws_size,
                              hipStream_t stream) {
    const float* x  = (const float*)d_in[0];
    // d_in[1] = adj (UNUSED by reference), d_in[2] = mask (UNUSED)
    const float* W1 = (const float*)d_in[3];
    const float* b1 = (const float*)d_in[4];
    const float* W2 = (const float*)d_in[5];
    const float* b2 = (const float*)d_in[6];
    const float* W3 = (const float*)d_in[7];
    const float* b3 = (const float*)d_in[8];
    float* out = (float*)d_out;

    // single self-sufficient launch; 512 blocks x 512 threads
    fused_kernel<<<BB * NN * NN / (64 * 64), 512, 0, stream>>>(
        x, W1, b1, W2, b2, W3, b3, out);
}

// Round 19
// 26.546 us; speedup vs baseline: 3.8022x; 3.8022x over previous
//
#include <hip/hip_runtime.h>

#define BB 2
#define NN 1024
#define FF 128
#define H1 64
#define H2 32
#define XPAD 136  // x-row stride in f16 (128+8)
#define PAD 72    // p-row stride in f16 (64+8)

typedef __attribute__((ext_vector_type(4))) _Float16 half4;   // 4 f16 (8B)
typedef __attribute__((ext_vector_type(8))) _Float16 half8;   // 8 f16 (4 VGPR)
typedef __attribute__((ext_vector_type(16))) float f32x16;    // 32x32 MFMA acc
typedef __attribute__((ext_vector_type(2))) float f32x2;      // v_pk_*_f32

// e = relu(a + b) in packed f16: 4x v_pk_add_f16 + 4x v_pk_max_f16
__device__ inline half8 addrelu8(half8 a, half8 b) {
    half8 s = a + b;
    const half8 z = {};
    return __builtin_elementwise_max(s, z);
}

// ---------------------------------------------------------------------------
// ZERO-SYNC full fusion, v9: dual-row interleaved phase B.
// R18 closed the decomposition: cold ~5.9 + warm stage+A ~5.2 + B ~11.7 =
// 22.8us. B's honest arithmetic: 3.2us VALU issue + 0.85us MFMA vs 11.7
// measured, at OccupancyPercent ~22% (~1.8 waves/SIMD) -> ~300cy/step of
// EXPOSED LATENCY (ds_read ~120cy + 4-deep MFMA ~128cy chains barely
// covered at 2 waves/SIMD). R17's ILP attempt failed by adding +32 regs of
// qj state; v9 gets dual dep-chains register-cheap: each wave runs TWO
// independent i-row chains (rows u and u+8) SHARING qj/wa/ci/w32.
// Per iter: prefetch next row-pair, 2 E-builds, 2 interleaved 4-MFMA
// chains, 2 epilogues. Stage/phase A/constants byte-identical to R13;
// per-output arithmetic identical -> absmax unchanged.
// Pre-commit: null kills the B-latency theory -> R20 declares or
// restructures occupancy.
// ---------------------------------------------------------------------------
__global__ __launch_bounds__(512, 2) void fused_kernel(
    const float* __restrict__ x, const float* __restrict__ W1,
    const float* __restrict__ b1, const float* __restrict__ W2,
    const float* __restrict__ b2, const float* __restrict__ W3,
    const float* __restrict__ b3, float* __restrict__ out)
{
    __shared__ __align__(16) _Float16 xlds[128][XPAD];  // 34.8 KB staged x
    __shared__ __align__(16) _Float16 plds[64][PAD];    // 9.2 KB pib rows
    __shared__ __align__(16) _Float16 pjlds[64][PAD];   // 9.2 KB pj rows

    const int tid  = threadIdx.x;
    const int lane = tid & 63;
    const int wv   = tid >> 6;                // 0..7
    const int bid  = blockIdx.x;

    const int b   = bid >> 8;                 // 256 blocks per batch
    const int rem = bid & 255;
    const int i0  = (rem >> 4) * 64;          // 16 i-tiles (64 rows each)
    const int j0  = (rem & 15) * 64;          // 16 j-tiles (64 cols each)
    const int jn  = lane & 31;                // m/n lane index
    const int hi  = lane >> 5;                // k-group half
    const int m   = jn;

    // ============ stage: 128 x-rows -> xlds (coalesced, f16) ==============
    {
        const int xb_i = b * NN + i0, xb_j = b * NN + j0 - 64;
        #pragma unroll
        for (int it = 0; it < 8; ++it) {
            const int idx = tid + it * 512;
            const int row = idx >> 5, c4 = (idx & 31) * 4;
            const int gr  = (row < 64 ? xb_i : xb_j) + row;
            const float4 v = *(const float4*)(x + (size_t)gr * FF + c4);
            half4 hv = {(_Float16)v.x, (_Float16)v.y,
                        (_Float16)v.z, (_Float16)v.w};
            *(half4*)&xlds[row][c4] = hv;
        }
    }
    __syncthreads();

    // ============ phase A: 8 gemm units, ONE per wave (balanced) ==========
    {
        const int xrow0 = ((wv & 2) ? 32 : 0) + ((wv & 4) ? 64 : 0);
        const int htile = wv & 1;
        const int koff  = (wv & 4) ? 0 : FF;
        _Float16* dstbase = (wv & 4) ? &pjlds[xrow0 - 64][0] : &plds[xrow0][0];
        const float* bias = (wv & 4) ? nullptr : b1;

        f32x16 acc = {};
        #pragma unroll
        for (int ks = 0; ks < 8; ++ks) {
            const int k0 = ks * 16 + hi * 8;
            half8 af;
            const float* wb = W1 + (size_t)(koff + k0) * H1 + htile * 32 + m;
            #pragma unroll
            for (int e = 0; e < 8; ++e)
                af[e] = (_Float16)wb[(size_t)e * H1];     // coalesced per e
            const half8 bf = *(const half8*)&xlds[xrow0 + m][k0];
            acc = __builtin_amdgcn_mfma_f32_32x32x16_f16(af, bf, acc, 0, 0, 0);
        }
        _Float16* drow = dstbase + (size_t)m * PAD;       // D col -> LDS row
        #pragma unroll
        for (int q = 0; q < 4; ++q) {                     // packed b64 stores
            half4 hv;
            #pragma unroll
            for (int jj = 0; jj < 4; ++jj) {
                const int r  = q * 4 + jj;                // hl=(r&3)+8(r>>2)+4hi
                const int hg = htile * 32 + 8 * q + 4 * hi + jj;
                float v = acc[r];
                if (bias) v += bias[hg];
                hv[jj] = (_Float16)v;
            }
            *(half4*)(drow + htile * 32 + 8 * q + 4 * hi) = hv;
        }
    }

    // ============ per-wave edge init (weights straight from global) =======
    half8 wa[4];
    #pragma unroll
    for (int c4 = 0; c4 < 4; ++c4)
        #pragma unroll
        for (int e = 0; e < 8; ++e)
            wa[c4][e] = (_Float16)W2[(16 * c4 + hi * 8 + e) * H2 + jn];

    f32x16 ci;
    #pragma unroll
    for (int r = 0; r < 16; ++r) {           // D row mapping [m74/m101]
        const int row = (r & 3) + 8 * (r >> 2) + 4 * hi;
        ci[r] = b2[row];
    }
    // W3 paired for the packed epilogue (R10 layout, verified)
    f32x2 w32[8];
    #pragma unroll
    for (int q = 0; q < 8; ++q) {
        const int row = ((2 * q) & 3) + 8 * (q >> 1) + 4 * hi;
        w32[q] = (f32x2){W3[row], W3[row + 1]};
    }
    const float b3v = b3[0];

    __syncthreads();   // phase A LDS writes visible to all waves

    // wave's phase-B assignment: row-group (wv>>1)*16, j-half (wv&1)*32
    const int rowgrp = wv >> 1;
    const int jhalf  = wv & 1;

    // B-frags (pj side) from LDS: row jhalf*32+jn, k-slices 16c + hi*8
    const _Float16* pr = &pjlds[jhalf * 32 + jn][hi * 8];
    const half8 qj0 = *(const half8*)(pr);
    const half8 qj1 = *(const half8*)(pr + 16);
    const half8 qj2 = *(const half8*)(pr + 32);
    const half8 qj3 = *(const half8*)(pr + 48);

    // R10 packed epilogue (incl. cross-half shfl)
    auto epi = [&](const f32x16& dd) -> float {
        const f32x2 z2 = {0.f, 0.f};
        f32x2 s[4] = {z2, z2, z2, z2};
        #pragma unroll
        for (int q = 0; q < 8; ++q) {
            f32x2 dp = {dd[2 * q], dd[2 * q + 1]};
            dp = __builtin_elementwise_max(dp, z2);
            s[q & 3] = __builtin_elementwise_fma(dp, w32[q], s[q & 3]);
        }
        const f32x2 t01 = s[0] + s[1];
        const f32x2 t23 = s[2] + s[3];
        const f32x2 tt  = t01 + t23;
        float p = tt[0] + tt[1];
        p += __shfl_xor(p, 32);   // lane-halves hold complementary rows
        return p;
    };

    // ============ phase B: 8 iters, dual independent row-chains ===========
    // chain A: rows rowgrp*16 + u        (u = 0..7)
    // chain B: rows rowgrp*16 + 8 + u
    const _Float16* irbase = &plds[rowgrp * 16][hi * 8];
    float* obase = out + (size_t)(b * NN + i0 + rowgrp * 16) * NN
                       + j0 + jhalf * 32 + jn;

    // prologue: load rows 0 and 8
    half8 cA0 = *(const half8*)(irbase);
    half8 cA1 = *(const half8*)(irbase + 16);
    half8 cA2 = *(const half8*)(irbase + 32);
    half8 cA3 = *(const half8*)(irbase + 48);
    const _Float16* irB0 = irbase + 8 * PAD;
    half8 cB0 = *(const half8*)(irB0);
    half8 cB1 = *(const half8*)(irB0 + 16);
    half8 cB2 = *(const half8*)(irB0 + 32);
    half8 cB3 = *(const half8*)(irB0 + 48);
    half8 nA0, nA1, nA2, nA3, nB0, nB1, nB2, nB3;
    float peA = 0.f, peB = 0.f;

    #pragma unroll 1
    for (int u = 0; u < 8; ++u) {
        // 1. prefetch next row pair (u+1, u+9)
        if (u < 7) {
            const _Float16* a = irbase + (u + 1) * PAD;
            const _Float16* bp = irbase + (u + 9) * PAD;
            nA0 = *(const half8*)(a);
            nA1 = *(const half8*)(a + 16);
            nA2 = *(const half8*)(a + 32);
            nA3 = *(const half8*)(a + 48);
            nB0 = *(const half8*)(bp);
            nB1 = *(const half8*)(bp + 16);
            nB2 = *(const half8*)(bp + 32);
            nB3 = *(const half8*)(bp + 48);
        }
        // 2. E-builds for both chains (c* die into e*)
        const half8 eA0 = addrelu8(qj0, cA0);
        const half8 eA1 = addrelu8(qj1, cA1);
        const half8 eA2 = addrelu8(qj2, cA2);
        const half8 eA3 = addrelu8(qj3, cA3);
        const half8 eB0 = addrelu8(qj0, cB0);
        const half8 eB1 = addrelu8(qj1, cB1);
        const half8 eB2 = addrelu8(qj2, cB2);
        const half8 eB3 = addrelu8(qj3, cB3);
        // 3. two INDEPENDENT 4-MFMA chains, interleaved (2x matrix ILP)
        f32x16 dA, dB;
        dA = __builtin_amdgcn_mfma_f32_32x32x16_f16(wa[0], eA0, ci, 0, 0, 0);
        dB = __builtin_amdgcn_mfma_f32_32x32x16_f16(wa[0], eB0, ci, 0, 0, 0);
        dA = __builtin_amdgcn_mfma_f32_32x32x16_f16(wa[1], eA1, dA, 0, 0, 0);
        dB = __builtin_amdgcn_mfma_f32_32x32x16_f16(wa[1], eB1, dB, 0, 0, 0);
        dA = __builtin_amdgcn_mfma_f32_32x32x16_f16(wa[2], eA2, dA, 0, 0, 0);
        dB = __builtin_amdgcn_mfma_f32_32x32x16_f16(wa[2], eB2, dB, 0, 0, 0);
        dA = __builtin_amdgcn_mfma_f32_32x32x16_f16(wa[3], eA3, dA, 0, 0, 0);
        dB = __builtin_amdgcn_mfma_f32_32x32x16_f16(wa[3], eB3, dB, 0, 0, 0);
        // 4. epilogues (independent of each other)
        const float pA = epi(dA);
        const float pB = epi(dB);
        if (u & 1) {   // store pairs (u-1,u) and (u+7,u+8) via hi-trick
            obase[(size_t)(u - 1 + hi) * NN] = (hi ? pA : peA) + b3v;
            obase[(size_t)(u + 7 + hi) * NN] = (hi ? pB : peB) + b3v;
        } else {
            peA = pA;
            peB = pB;
        }
        cA0 = nA0; cA1 = nA1; cA2 = nA2; cA3 = nA3;
        cB0 = nB0; cB1 = nB1; cB2 = nB2; cB3 = nB3;
    }
}

extern "C" void kernel_launch(void* const* d_in, const int* in_sizes, int n_in,
                              void* d_out, int out_size, void* d_ws, size_t ws_size,
                              hipStream_t stream) {
    const float* x  = (const float*)d_in[0];
    // d_in[1] = adj (UNUSED by reference), d_in[2] = mask (UNUSED)
    const float* W1 = (const float*)d_in[3];
    const float* b1 = (const float*)d_in[4];
    const float* W2 = (const float*)d_in[5];
    const float* b2 = (const float*)d_in[6];
    const float* W3 = (const float*)d_in[7];
    const float* b3 = (const float*)d_in[8];
    float* out = (float*)d_out;

    // single self-sufficient launch; 512 blocks x 512 threads
    fused_kernel<<<BB * NN * NN / (64 * 64), 512, 0, stream>>>(
        x, W1, b1, W2, b2, W3, b3, out);
}

// Round 20
// 23.066 us; speedup vs baseline: 4.3758x; 1.1509x over previous
//
#include <hip/hip_runtime.h>

#define BB 2
#define NN 1024
#define FF 128
#define H1 64
#define H2 32
#define XPAD 136  // x-row stride in f16 (128+8)
#define PAD 72    // p-row stride in f16 (64+8)

typedef __attribute__((ext_vector_type(4))) _Float16 half4;   // 4 f16 (8B)
typedef __attribute__((ext_vector_type(8))) _Float16 half8;   // 8 f16 (4 VGPR)
typedef __attribute__((ext_vector_type(16))) float f32x16;    // 32x32 MFMA acc
typedef __attribute__((ext_vector_type(2))) float f32x2;      // v_pk_*_f32

// e = relu(a + b) in packed f16: 4x v_pk_add_f16 + 4x v_pk_max_f16
__device__ inline half8 addrelu8(half8 a, half8 b) {
    half8 s = a + b;
    const half8 z = {};
    return __builtin_elementwise_max(s, z);
}

// ---------------------------------------------------------------------------
// FINAL (R20) = R13 exactly — the session best (22.8us), reverted from
// R19's dual-chain regression (26.5).
//
// Session ledger (26.9 -> 22.8):
//   WINS (all memory-traffic / balance):  k-split precompute (R2, -1.6),
//     zero-sync single-launch fusion + coalesced LDS x-stage (R7+R8, -6.4
//     vs R7), packed-f32 epilogue diet (R10, -1.0), 8-wave balanced
//     phase A + 64x64 tiles (R12, -1.8).
//   STRUCTURAL FACTS (instrumented): cold first-touch ~5.9us + warm
//     stage+A ~5.2us + phase B ~11.7us = 22.8 (R14/R15/R18 REPS algebra).
//     Inter-block sync is 10-20x the work on this chip (coop barrier
//     127us / acquire-poll 88us / relaxed-poll 61us: R3/R4/R6).
//   DEAD THEORIES for phase B's ~3x inflation: mov overhead (R10/R11),
//     ordering (R11), launch-bounds/AGPR (R13/R14: VGPR=72 under a
//     256-reg budget), LDS broadcast BW (R17: halving reads regressed),
//     exposed latency via reg-bought ILP (R17 +2.0, R19 +3.7 — ILP
//     bought with +60-90 live regs always nets negative here).
//   Remaining gap (to ~12-14us arithmetic floor) requires disasm-level
//   instruction attribution unavailable in this loop.
// ---------------------------------------------------------------------------
__global__ __launch_bounds__(512, 2) void fused_kernel(
    const float* __restrict__ x, const float* __restrict__ W1,
    const float* __restrict__ b1, const float* __restrict__ W2,
    const float* __restrict__ b2, const float* __restrict__ W3,
    const float* __restrict__ b3, float* __restrict__ out)
{
    __shared__ __align__(16) _Float16 xlds[128][XPAD];  // 34.8 KB staged x
    __shared__ __align__(16) _Float16 plds[64][PAD];    // 9.2 KB pib rows
    __shared__ __align__(16) _Float16 pjlds[64][PAD];   // 9.2 KB pj rows

    const int tid  = threadIdx.x;
    const int lane = tid & 63;
    const int wv   = tid >> 6;                // 0..7
    const int bid  = blockIdx.x;

    const int b   = bid >> 8;                 // 256 blocks per batch
    const int rem = bid & 255;
    const int i0  = (rem >> 4) * 64;          // 16 i-tiles (64 rows each)
    const int j0  = (rem & 15) * 64;          // 16 j-tiles (64 cols each)
    const int jn  = lane & 31;                // m/n lane index
    const int hi  = lane >> 5;                // k-group half
    const int m   = jn;

    // ============ stage: 128 x-rows -> xlds (coalesced, f16) ==============
    // rows 0..63 = i-rows i0..i0+63; rows 64..127 = j-rows j0..j0+63.
    {
        const int xb_i = b * NN + i0, xb_j = b * NN + j0 - 64;
        #pragma unroll
        for (int it = 0; it < 8; ++it) {
            const int idx = tid + it * 512;
            const int row = idx >> 5, c4 = (idx & 31) * 4;
            const int gr  = (row < 64 ? xb_i : xb_j) + row;
            const float4 v = *(const float4*)(x + (size_t)gr * FF + c4);
            half4 hv = {(_Float16)v.x, (_Float16)v.y,
                        (_Float16)v.z, (_Float16)v.w};
            *(half4*)&xlds[row][c4] = hv;
        }
    }
    __syncthreads();

    // ============ phase A: 8 gemm units, ONE per wave (balanced) ==========
    //   wv0/1: pib rows  0-31 (htile 0/1)   wv2/3: pib rows 32-63
    //   wv4/5: pj  rows  0-31               wv6/7: pj  rows 32-63
    {
        const int xrow0 = ((wv & 2) ? 32 : 0) + ((wv & 4) ? 64 : 0);
        const int htile = wv & 1;
        const int koff  = (wv & 4) ? 0 : FF;
        _Float16* dstbase = (wv & 4) ? &pjlds[xrow0 - 64][0] : &plds[xrow0][0];
        const float* bias = (wv & 4) ? nullptr : b1;

        f32x16 acc = {};
        #pragma unroll
        for (int ks = 0; ks < 8; ++ks) {
            const int k0 = ks * 16 + hi * 8;
            half8 af;
            const float* wb = W1 + (size_t)(koff + k0) * H1 + htile * 32 + m;
            #pragma unroll
            for (int e = 0; e < 8; ++e)
                af[e] = (_Float16)wb[(size_t)e * H1];     // coalesced per e
            const half8 bf = *(const half8*)&xlds[xrow0 + m][k0];
            acc = __builtin_amdgcn_mfma_f32_32x32x16_f16(af, bf, acc, 0, 0, 0);
        }
        _Float16* drow = dstbase + (size_t)m * PAD;       // D col -> LDS row
        #pragma unroll
        for (int q = 0; q < 4; ++q) {                     // packed b64 stores
            half4 hv;
            #pragma unroll
            for (int jj = 0; jj < 4; ++jj) {
                const int r  = q * 4 + jj;                // hl=(r&3)+8(r>>2)+4hi
                const int hg = htile * 32 + 8 * q + 4 * hi + jj;
                float v = acc[r];
                if (bias) v += bias[hg];
                hv[jj] = (_Float16)v;
            }
            *(half4*)(drow + htile * 32 + 8 * q + 4 * hi) = hv;
        }
    }

    // ============ per-wave edge init (weights straight from global) =======
    half8 wa[4];
    #pragma unroll
    for (int c4 = 0; c4 < 4; ++c4)
        #pragma unroll
        for (int e = 0; e < 8; ++e)
            wa[c4][e] = (_Float16)W2[(16 * c4 + hi * 8 + e) * H2 + jn];

    f32x16 ci;
    #pragma unroll
    for (int r = 0; r < 16; ++r) {           // D row mapping [m74/m101]
        const int row = (r & 3) + 8 * (r >> 2) + 4 * hi;
        ci[r] = b2[row];
    }
    // W3 paired for the packed epilogue (R10 layout, verified)
    f32x2 w32[8];
    #pragma unroll
    for (int q = 0; q < 8; ++q) {
        const int row = ((2 * q) & 3) + 8 * (q >> 1) + 4 * hi;
        w32[q] = (f32x2){W3[row], W3[row + 1]};
    }
    const float b3v = b3[0];

    __syncthreads();   // phase A LDS writes visible to all waves

    // wave's phase-B assignment: row-group (wv>>1)*16, j-half (wv&1)*32
    const int rowgrp = wv >> 1;
    const int jhalf  = wv & 1;

    // B-frags (pj side) from LDS: row jhalf*32+jn, k-slices 16c + hi*8
    const _Float16* pr = &pjlds[jhalf * 32 + jn][hi * 8];
    const half8 qj0 = *(const half8*)(pr);
    const half8 qj1 = *(const half8*)(pr + 16);
    const half8 qj2 = *(const half8*)(pr + 32);
    const half8 qj3 = *(const half8*)(pr + 48);

    // R10 packed epilogue (incl. cross-half shfl)
    auto epi = [&](const f32x16& dd) -> float {
        const f32x2 z2 = {0.f, 0.f};
        f32x2 s[4] = {z2, z2, z2, z2};
        #pragma unroll
        for (int q = 0; q < 8; ++q) {
            f32x2 dp = {dd[2 * q], dd[2 * q + 1]};
            dp = __builtin_elementwise_max(dp, z2);
            s[q & 3] = __builtin_elementwise_fma(dp, w32[q], s[q & 3]);
        }
        const f32x2 t01 = s[0] + s[1];
        const f32x2 t23 = s[2] + s[3];
        const f32x2 tt  = t01 + t23;
        float p = tt[0] + tt[1];
        p += __shfl_xor(p, 32);   // lane-halves hold complementary rows
        return p;
    };

    // ============ phase B: software-pipelined 16 row-steps ================
    const _Float16* irbase = &plds[rowgrp * 16][hi * 8];
    float* obase = out + (size_t)(b * NN + i0 + rowgrp * 16) * NN
                       + j0 + jhalf * 32 + jn;

    // ---- prologue: e(0), dP = mfma(step 0), e(1) ----
    half8 e0 = addrelu8(qj0, *(const half8*)(irbase));
    half8 e1 = addrelu8(qj1, *(const half8*)(irbase + 16));
    half8 e2 = addrelu8(qj2, *(const half8*)(irbase + 32));
    half8 e3 = addrelu8(qj3, *(const half8*)(irbase + 48));
    f32x16 dP;
    dP = __builtin_amdgcn_mfma_f32_32x32x16_f16(wa[0], e0, ci, 0, 0, 0);
    dP = __builtin_amdgcn_mfma_f32_32x32x16_f16(wa[1], e1, dP, 0, 0, 0);
    dP = __builtin_amdgcn_mfma_f32_32x32x16_f16(wa[2], e2, dP, 0, 0, 0);
    dP = __builtin_amdgcn_mfma_f32_32x32x16_f16(wa[3], e3, dP, 0, 0, 0);
    {
        const _Float16* ir = irbase + PAD;
        e0 = addrelu8(qj0, *(const half8*)(ir));
        e1 = addrelu8(qj1, *(const half8*)(ir + 16));
        e2 = addrelu8(qj2, *(const half8*)(ir + 32));
        e3 = addrelu8(qj3, *(const half8*)(ir + 48));
    }
    float pe = 0.f;

    #pragma unroll 2
    for (int t = 1; t < 16; ++t) {
        // 1. prefetch LDS row for step t+1
        const int tn = (t < 15) ? t + 1 : 15;
        const _Float16* ir = irbase + tn * PAD;
        const half8 m0 = *(const half8*)(ir);
        const half8 m1 = *(const half8*)(ir + 16);
        const half8 m2 = *(const half8*)(ir + 32);
        const half8 m3 = *(const half8*)(ir + 48);
        // 2. MFMA chain of step t on e (built last iteration)
        f32x16 d;
        d = __builtin_amdgcn_mfma_f32_32x32x16_f16(wa[0], e0, ci, 0, 0, 0);
        d = __builtin_amdgcn_mfma_f32_32x32x16_f16(wa[1], e1, d,  0, 0, 0);
        d = __builtin_amdgcn_mfma_f32_32x32x16_f16(wa[2], e2, d,  0, 0, 0);
        d = __builtin_amdgcn_mfma_f32_32x32x16_f16(wa[3], e3, d,  0, 0, 0);
        // 3. epilogue of step t-1 (independent of the chain above)
        const float p = epi(dP);
        if ((t - 1) & 1) {                   // t even: store pair (t-2, t-1)
            const float v = hi ? p : pe;     // hi half stores the odd row
            obase[(size_t)(t - 2 + hi) * NN] = v + b3v;
        } else {
            pe = p;
        }
        // 4. build E for step t+1 (independent of the chain above)
        e0 = addrelu8(qj0, m0);
        e1 = addrelu8(qj1, m1);
        e2 = addrelu8(qj2, m2);
        e3 = addrelu8(qj3, m3);
        dP = d;
    }
    // ---- tail: epilogue of step 15, store pair (14,15) ----
    {
        const float p = epi(dP);
        const float v = hi ? p : pe;
        obase[(size_t)(14 + hi) * NN] = v + b3v;
    }
}

extern "C" void kernel_launch(void* const* d_in, const int* in_sizes, int n_in,
                              void* d_out, int out_size, void* d_ws, size_t ws_size,
                              hipStream_t stream) {
    const float* x  = (const float*)d_in[0];
    // d_in[1] = adj (UNUSED by reference), d_in[2] = mask (UNUSED)
    const float* W1 = (const float*)d_in[3];
    const float* b1 = (const float*)d_in[4];
    const float* W2 = (const float*)d_in[5];
    const float* b2 = (const float*)d_in[6];
    const float* W3 = (const float*)d_in[7];
    const float* b3 = (const float*)d_in[8];
    float* out = (float*)d_out;

    // single self-sufficient launch; 512 blocks x 512 threads
    fused_kernel<<<BB * NN * NN / (64 * 64), 512, 0, stream>>>(
        x, W1, b1, W2, b2, W3, b3, out);
}